// Round 9
// baseline (372.046 us; speedup 1.0000x reference)
//
#include <hip/hip_runtime.h>
#include <math.h>

#define HEADS 4
#define CH 256
#define HC 1024
#define NSLICE 8
#define NEG_SLOPE 0.2f
#define EPSQ 1e-16f
#define AGG_T 128  // CSR slots per 16-lane group

typedef __attribute__((ext_vector_type(8))) short bf16x8;
typedef __attribute__((ext_vector_type(4))) float f32x4;

static inline int cdiv(int a, int b) { return (a + b - 1) / b; }

__device__ __forceinline__ unsigned short f2bf(float f) {
  unsigned u = __float_as_uint(f);
  u += 0x7FFFu + ((u >> 16) & 1u);  // RNE
  return (unsigned short)(u >> 16);
}
__device__ __forceinline__ float bf2f(unsigned short s) {
  return __uint_as_float(((unsigned)s) << 16);
}
__device__ __forceinline__ void gload_lds16(const void* g, void* l) {
  __builtin_amdgcn_global_load_lds((const __attribute__((address_space(1))) void*)g,
                                   (__attribute__((address_space(3))) void*)l, 16, 0, 0);
}

// ---------------- CSR build ----------------
__global__ void k_count(const int* __restrict__ ei, int E, int ET, int* __restrict__ cnt) {
  int e = blockIdx.x * blockDim.x + threadIdx.x;
  if (e >= ET) return;
  int d = (e < E) ? ei[E + e] : (e - E);
  atomicAdd(&cnt[d], 1);
}

__global__ __launch_bounds__(1024) void k_scan(const int* __restrict__ counts,
                                               int* __restrict__ offsets, int n) {
  __shared__ int wsum[16];
  __shared__ int carry_s;
  int lane = threadIdx.x & 63, wv = threadIdx.x >> 6;
  if (threadIdx.x == 0) carry_s = 0;
  __syncthreads();
  for (int base = 0; base < n; base += 1024) {
    int i = base + threadIdx.x;
    int orig = (i < n) ? counts[i] : 0;
    int v = orig;
#pragma unroll
    for (int off = 1; off < 64; off <<= 1) {
      int t = __shfl_up(v, off);
      if (lane >= off) v += t;
    }
    if (lane == 63) wsum[wv] = v;
    __syncthreads();
    int carry = carry_s;
    int wpre = 0;
#pragma unroll
    for (int w = 0; w < 16; w++) wpre += (w < wv) ? wsum[w] : 0;
    int incl = v + wpre;
    if (i < n) offsets[i] = carry + incl - orig;
    __syncthreads();
    if (threadIdx.x == 1023) carry_s = carry + incl;
    __syncthreads();
  }
  if (threadIdx.x == 0) offsets[n] = carry_s;
}

__global__ void k_fill(const int* __restrict__ ei, int E, int ET,
                       const int* __restrict__ offsets, int* __restrict__ cursor,
                       int2* __restrict__ esd) {
  int e = blockIdx.x * blockDim.x + threadIdx.x;
  if (e >= ET) return;
  int s = (e < E) ? ei[e] : (e - E);
  int d = (e < E) ? ei[E + e] : (e - E);
  int pos = offsets[d] + atomicAdd(&cursor[d], 1);
  esd[pos] = make_int2(s, d);
}

// ---------------- W transpose + cast ----------------
__global__ __launch_bounds__(256) void k_transpose_w(const float* __restrict__ W,
                                                     unsigned short* __restrict__ Wt, int K) {
  __shared__ float tile[32][33];
  int tx = threadIdx.x & 31, ty = threadIdx.x >> 5;
  int k0 = blockIdx.x * 32, n0 = blockIdx.y * 32;
#pragma unroll
  for (int r = ty; r < 32; r += 8) tile[r][tx] = W[(size_t)(k0 + r) * HC + n0 + tx];
  __syncthreads();
#pragma unroll
  for (int r = ty; r < 32; r += 8)
    Wt[(size_t)(n0 + r) * K + k0 + tx] = f2bf(tile[tx][r]);
}

// ---------------- cast fp32 -> bf16 ----------------
__global__ void k_cast_bf16(const float* __restrict__ in, unsigned short* __restrict__ out,
                            int n) {
  int i = (blockIdx.x * blockDim.x + threadIdx.x) * 8;
  if (i >= n) return;
  float4 a = *(const float4*)&in[i];
  float4 b = *(const float4*)&in[i + 4];
  ushort4 lo = make_ushort4(f2bf(a.x), f2bf(a.y), f2bf(a.z), f2bf(a.w));
  ushort4 hi = make_ushort4(f2bf(b.x), f2bf(b.y), f2bf(b.z), f2bf(b.w));
  *(ushort4*)&out[i] = lo;
  *(ushort4*)&out[i + 4] = hi;
}

// ---------------- bf16 MFMA GEMM, epilogue writes slice-major hsl[c][n][128] ----
__global__ __launch_bounds__(256) void k_gemm_mfma(const unsigned short* __restrict__ A,
                                                   const unsigned short* __restrict__ Bt,
                                                   unsigned short* __restrict__ hsl, int M,
                                                   int K) {
  __shared__ unsigned short sA[2][128 * 32];
  __shared__ unsigned short sB[2][128 * 32];
  int t = threadIdx.x;
  int lane = t & 63, wv = t >> 6;
  int wr = wv >> 1, wc = wv & 1;
  int row0 = blockIdx.x * 128, col0 = blockIdx.y * 128;
  int l15 = lane & 15, l4 = lane >> 4;

  f32x4 acc[4][4] = {};

  auto stage = [&](unsigned short* sdst, const unsigned short* g, int grow0, int rowmax,
                   int k0) {
#pragma unroll
    for (int q = 0; q < 2; ++q) {
      int r = grow0 + q * 64 + (t >> 2);
      if (r > rowmax) r = rowmax;
      const unsigned short* gp = g + (size_t)r * K + k0 + (t & 3) * 8;
      gload_lds16(gp, sdst + q * 2048 + t * 8);
    }
  };

  int KT = K / 32;
  stage(sA[0], A, row0, M - 1, 0);
  stage(sB[0], Bt, col0, HC - 1, 0);
  int cur = 0;
  for (int kt = 0; kt < KT; ++kt) {
    __syncthreads();
    if (kt + 1 < KT) {
      stage(sA[cur ^ 1], A, row0, M - 1, (kt + 1) * 32);
      stage(sB[cur ^ 1], Bt, col0, HC - 1, (kt + 1) * 32);
    }
    bf16x8 af[4], bfr[4];
#pragma unroll
    for (int i = 0; i < 4; i++)
      af[i] = *(bf16x8*)&sA[cur][(wr * 64 + i * 16 + l15) * 32 + l4 * 8];
#pragma unroll
    for (int j = 0; j < 4; j++)
      bfr[j] = *(bf16x8*)&sB[cur][(wc * 64 + j * 16 + l15) * 32 + l4 * 8];
#pragma unroll
    for (int i = 0; i < 4; i++)
#pragma unroll
      for (int j = 0; j < 4; j++)
        acc[i][j] = __builtin_amdgcn_mfma_f32_16x16x32_bf16(af[i], bfr[j], acc[i][j], 0, 0, 0);
    cur ^= 1;
  }
#pragma unroll
  for (int i = 0; i < 4; i++) {
#pragma unroll
    for (int j = 0; j < 4; j++) {
      int col = col0 + wc * 64 + j * 16 + l15;
      int head = col >> 8;
      int c = (col >> 5) & 7;
      int jj = col & 31;
      size_t sbase = ((size_t)c * M) * 128 + (head << 5) + jj;
#pragma unroll
      for (int r = 0; r < 4; r++) {
        int row = row0 + wr * 64 + i * 16 + l4 * 4 + r;
        if (row < M) hsl[sbase + (size_t)row * 128] = f2bf(acc[i][j][r]);
      }
    }
  }
}

// ---------------- per-node logits from slice-major hsl ----------------
__global__ __launch_bounds__(256) void k_logits(const unsigned short* __restrict__ hsl,
                                                const float* __restrict__ as_,
                                                const float* __restrict__ ad_,
                                                float* __restrict__ es, float* __restrict__ ed,
                                                int M) {
  __shared__ float lds_s[4][64];
  __shared__ float lds_d[4][64];
  int n = blockIdx.x;
  int t = threadIdx.x;
  int c = t >> 5, chunk = t & 31;
  int head = chunk >> 3, q = chunk * 4;
  ushort4 hv = *(const ushort4*)&hsl[((size_t)c * M + n) * 128 + q];
  int ch = head * 256 + c * 32 + (q & 31);
  float4 s4 = *(const float4*)&as_[ch];
  float4 d4 = *(const float4*)&ad_[ch];
  float h0 = bf2f(hv.x), h1 = bf2f(hv.y), h2 = bf2f(hv.z), h3 = bf2f(hv.w);
  float ds = h0 * s4.x + h1 * s4.y + h2 * s4.z + h3 * s4.w;
  float dd = h0 * d4.x + h1 * d4.y + h2 * d4.z + h3 * d4.w;
  int g = c * 8 + (chunk & 7);
  lds_s[head][g] = ds;
  lds_d[head][g] = dd;
  __syncthreads();
  int wv = t >> 6, l = t & 63;
  float vs = lds_s[wv][l];
  float vd = lds_d[wv][l];
#pragma unroll
  for (int off = 32; off; off >>= 1) {
    vs += __shfl_xor(vs, off);
    vd += __shfl_xor(vd, off);
  }
  if (l == 0) {
    es[n * HEADS + wv] = vs;
    ed[n * HEADS + wv] = vd;
  }
}

// ---------------- slot-ordered edge exp ----------------
__global__ void k_edge_exp(const int2* __restrict__ esd, int ET,
                           const float4* __restrict__ es4, const float4* __restrict__ ed4,
                           float4* __restrict__ exs4) {
  int k = blockIdx.x * blockDim.x + threadIdx.x;
  if (k >= ET) return;
  int2 sd = esd[k];
  float4 a = es4[sd.x], b = ed4[sd.y];
  float v0 = a.x + b.x, v1 = a.y + b.y, v2 = a.z + b.z, v3 = a.w + b.w;
  v0 = v0 > 0.f ? v0 : NEG_SLOPE * v0;
  v1 = v1 > 0.f ? v1 : NEG_SLOPE * v1;
  v2 = v2 > 0.f ? v2 : NEG_SLOPE * v2;
  v3 = v3 > 0.f ? v3 : NEG_SLOPE * v3;
  exs4[k] = make_float4(__expf(v0), __expf(v1), __expf(v2), __expf(v3));
}

// ---------------- per-node inverse denom ----------------
__global__ __launch_bounds__(256) void k_denom(const float* __restrict__ exs,
                                               const int* __restrict__ offsets,
                                               float* __restrict__ inva, int N) {
  int lane = threadIdx.x & 63;
  int n = blockIdx.x * 4 + (threadIdx.x >> 6);
  if (n >= N) return;
  int sub = lane >> 2, h = lane & 3;
  int k0 = offsets[n], k1 = offsets[n + 1];
  float sum = 0.f;
  for (int k = k0 + sub; k < k1; k += 16) sum += exs[k * 4 + h];
#pragma unroll
  for (int off = 4; off < 64; off <<= 1) sum += __shfl_xor(sum, off);
  if (lane < 4) inva[n * 4 + h] = 0.25f / (sum + EPSQ);
}

// ---------------- streaming segmented aggregation ----------------
// 16-lane group owns AGG_T contiguous CSR slots of slice c (= blockIdx.x&7,
// XCD round-robin). Per slot: broadcast int2{src,dst} + alpha dword (next-slot
// prefetched) + one coalesced 256B h-burst. On dst change: scale by prefetched
// inva (incl. 0.25 head-mean), 2 shfl head-sums, store (interior node) or
// atomicAdd (range-boundary partial) into zeroed fp32 out.
__global__ __launch_bounds__(256) void k_agg_stream(const unsigned short* __restrict__ hsl,
                                                    const float* __restrict__ exs,
                                                    const float* __restrict__ inva,
                                                    const int2* __restrict__ esd,
                                                    float* __restrict__ outf, int N, int ET,
                                                    int gps) {
  int c = blockIdx.x & 7;
  int gidx = (blockIdx.x >> 3) * 16 + (threadIdx.x >> 4);
  if (gidx >= gps) return;
  int kb = gidx * AGG_T;
  if (kb >= ET) return;
  int ke = kb + AGG_T;
  if (ke > ET) ke = ET;
  int q = threadIdx.x & 15;
  int hq = q >> 2;
  int oc = c * 32 + (q & 3) * 8;
  const unsigned short* sl = hsl + (size_t)c * N * 128;

  float acc[8] = {};
  int2 sd = esd[kb];
  float av = exs[kb * 4 + hq];
  int cur = sd.y;
  float ia = inva[cur * 4 + hq];
  bool first = true;

  auto flush = [&](int dst, bool atomic, float iav) {
    float v[8];
#pragma unroll
    for (int j = 0; j < 8; j++) {
      float tv = acc[j] * iav;
      tv += __shfl_xor(tv, 4);
      tv += __shfl_xor(tv, 8);
      v[j] = tv;
    }
    if (q < 4) {
      float* op = &outf[(size_t)dst * CH + oc];
      if (atomic) {
#pragma unroll
        for (int j = 0; j < 8; j++) atomicAdd(&op[j], v[j]);
      } else {
        *(float4*)op = make_float4(v[0], v[1], v[2], v[3]);
        *(float4*)(op + 4) = make_float4(v[4], v[5], v[6], v[7]);
      }
    }
  };

  for (int k = kb; k < ke; ++k) {
    int kn = (k + 1 < ke) ? k + 1 : k;
    int2 sd_n = esd[kn];
    float av_n = exs[kn * 4 + hq];
    bf16x8 hv = *(const bf16x8*)&sl[(size_t)sd.x * 128 + q * 8];
    if (sd.y != cur) {
      flush(cur, first, ia);
      first = false;
#pragma unroll
      for (int j = 0; j < 8; j++) acc[j] = 0.f;
      cur = sd.y;
      ia = inva[cur * 4 + hq];
    }
#pragma unroll
    for (int j = 0; j < 8; j++) acc[j] += av * bf2f((unsigned short)hv[j]);
    sd = sd_n;
    av = av_n;
  }
  flush(cur, true, ia);  // tail may extend into next range -> atomic
}

// ---------------- bias + cast epilogue ----------------
__global__ void k_bias(const float* __restrict__ outf, const float* __restrict__ bias,
                       unsigned short* __restrict__ obf, float* __restrict__ of, int total) {
  int i = (blockIdx.x * blockDim.x + threadIdx.x) * 4;
  if (i >= total) return;
  float4 v = *(const float4*)&outf[i];
  float4 b = *(const float4*)&bias[i & 255];
  v.x += b.x;
  v.y += b.y;
  v.z += b.z;
  v.w += b.w;
  if (of) {
    *(float4*)&of[i] = v;
  } else {
    ushort4 o = make_ushort4(f2bf(v.x), f2bf(v.y), f2bf(v.z), f2bf(v.w));
    *(ushort4*)&obf[i] = o;
  }
}

extern "C" void kernel_launch(void* const* d_in, const int* in_sizes, int n_in,
                              void* d_out, int out_size, void* d_ws, size_t ws_size,
                              hipStream_t stream) {
  const float* x = (const float*)d_in[0];
  const int* ei = (const int*)d_in[1];
  const float* W[3] = {(const float*)d_in[2], (const float*)d_in[6], (const float*)d_in[10]};
  const float* AS[3] = {(const float*)d_in[3], (const float*)d_in[7], (const float*)d_in[11]};
  const float* AD[3] = {(const float*)d_in[4], (const float*)d_in[8], (const float*)d_in[12]};
  const float* BI[3] = {(const float*)d_in[5], (const float*)d_in[9], (const float*)d_in[13]};
  const int N = in_sizes[0] / 512;
  const int E = in_sizes[1] / 2;
  const int ET = E + N;
  const int Kd[3] = {512, 256, 256};

  char* p = (char*)d_ws;
  auto alloc = [&](size_t bytes) {
    char* r = p;
    p += (bytes + 255) & ~(size_t)255;
    return (void*)r;
  };
  unsigned short* hsl = (unsigned short*)alloc((size_t)NSLICE * N * 128 * 2);
  unsigned short* axb = (unsigned short*)alloc((size_t)N * 512 * 2);
  unsigned short* actbf = (unsigned short*)alloc((size_t)N * CH * 2);
  float* outf = (float*)alloc((size_t)N * CH * 4);
  unsigned short* Wt[3];
  for (int i = 0; i < 3; i++) Wt[i] = (unsigned short*)alloc((size_t)HC * Kd[i] * 2);
  float* es = (float*)alloc((size_t)N * HEADS * 4);
  float* ed = (float*)alloc((size_t)N * HEADS * 4);
  float* exs = (float*)alloc((size_t)ET * HEADS * 4);
  float* inva = (float*)alloc((size_t)N * HEADS * 4);
  int* offsets = (int*)alloc((size_t)(N + 1) * 4);
  int* cursor = (int*)alloc((size_t)N * 4);
  int2* esd = (int2*)alloc((size_t)ET * 8);

  // ---- CSR build (shared by all 3 layers) ----
  hipMemsetAsync(cursor, 0, (size_t)N * 4, stream);
  k_count<<<cdiv(ET, 256), 256, 0, stream>>>(ei, E, ET, cursor);
  k_scan<<<1, 1024, 0, stream>>>(cursor, offsets, N);
  hipMemsetAsync(cursor, 0, (size_t)N * 4, stream);
  k_fill<<<cdiv(ET, 256), 256, 0, stream>>>(ei, E, ET, offsets, cursor, esd);

  // ---- weight transpose+cast, input cast ----
  for (int i = 0; i < 3; i++)
    k_transpose_w<<<dim3(Kd[i] / 32, HC / 32), 256, 0, stream>>>(W[i], Wt[i], Kd[i]);
  k_cast_bf16<<<cdiv(N * 512, 8 * 256), 256, 0, stream>>>(x, axb, N * 512);

  const unsigned short* ain = axb;
  int gps = cdiv(ET, AGG_T);                 // groups per slice
  int aggGrid = cdiv(gps, 16) * 8;           // 16 groups per block, x8 slices
  for (int layer = 0; layer < 3; ++layer) {
    int K = Kd[layer];
    k_gemm_mfma<<<dim3(cdiv(N, 128), HC / 128), 256, 0, stream>>>(ain, Wt[layer], hsl, N, K);
    k_logits<<<N, 256, 0, stream>>>(hsl, AS[layer], AD[layer], es, ed, N);
    k_edge_exp<<<cdiv(ET, 256), 256, 0, stream>>>(esd, ET, (const float4*)es,
                                                  (const float4*)ed, (float4*)exs);
    k_denom<<<cdiv(N, 4), 256, 0, stream>>>(exs, offsets, inva, N);
    hipMemsetAsync(outf, 0, (size_t)N * CH * 4, stream);
    k_agg_stream<<<aggGrid, 256, 0, stream>>>(hsl, exs, inva, esd, outf, N, ET, gps);
    if (layer < 2) {
      k_bias<<<cdiv(N * CH / 4, 256), 256, 0, stream>>>(outf, BI[layer], actbf,
                                                        (float*)nullptr, N * CH);
    } else {
      k_bias<<<cdiv(N * CH / 4, 256), 256, 0, stream>>>(outf, BI[layer],
                                                        (unsigned short*)nullptr,
                                                        (float*)d_out, N * CH);
    }
    ain = actbf;
  }
}